// Round 1
// 1604.217 us; speedup vs baseline: 1.1966x; 1.1966x over previous
//
#include <hip/hip_runtime.h>
#include <hip/hip_bf16.h>
#include <stdint.h>

typedef __bf16 bf16_t;
typedef __attribute__((ext_vector_type(8))) __bf16 bf16x8;
typedef __attribute__((ext_vector_type(4))) __bf16 bf16x4;
typedef __attribute__((ext_vector_type(4))) float f32x4;
#define LL long long

// ---- async global->LDS, 16B per lane. ldsptr must be wave-uniform. ----
__device__ __forceinline__ void gl_lds16(const bf16_t* g, bf16_t* s) {
  __builtin_amdgcn_global_load_lds(
      (const __attribute__((address_space(1))) void*)g,
      (__attribute__((address_space(3))) void*)s, 16, 0, 0);
}

__device__ __forceinline__ float sigm(float x) {
  return 1.0f / (1.0f + __expf(-x));
}
__device__ __forceinline__ float tanh_s(float x) {
  float e = __expf(-2.0f * fabsf(x));
  float t = (1.0f - e) / (1.0f + e);
  return copysignf(t, x);
}

// ======================= generic C = A @ B^T GEMM ========================
// A [M,K] bf16, B [N,K] bf16, bias fp32 [N]; tile BM x 128, BK=32.
// OUTBF=1: write bf16 to Cb + (fw[0] ? off1 : off0); else fp32 to Cf.
template<int BM, int OUTBF>
__global__ __launch_bounds__(256, 2)
void gemm_bt(const bf16_t* __restrict__ A, const bf16_t* __restrict__ B,
             const float* __restrict__ bias,
             bf16_t* __restrict__ Cb, float* __restrict__ Cf,
             int N, int K, const int* __restrict__ fw, LL off0, LL off1) {
  __shared__ bf16_t lds_a[BM * 32];
  __shared__ bf16_t lds_b[128 * 32];
  const int tid = threadIdx.x;
  const int w = tid >> 6, l = tid & 63;
  const LL m0 = (LL)blockIdx.x * BM;
  const LL n0 = (LL)blockIdx.y * 128;
  constexpr int MI = BM / 32;          // 16x16 acc tiles per wave in M
  const int wm = w & 1, wn = w >> 1;   // 2x2 wave grid
  f32x4 acc[MI][4] = {};

  const int srow = l >> 2;             // staging row within 16-row chunk
  const int scol = (l & 3) * 8;        // staging k-col (8 bf16 = 16B)

  for (int kt = 0; kt < K; kt += 32) {
    // stage A (BM/16 chunks of 16 rows) and B (8 chunks), 1KB per issue
    for (int c = w; c < BM / 16; c += 4)
      gl_lds16(A + (m0 + c * 16 + srow) * K + kt + scol, &lds_a[c * 512]);
#pragma unroll
    for (int j = 0; j < 2; ++j) {
      int c = w * 2 + j;
      gl_lds16(B + (n0 + c * 16 + srow) * K + kt + scol, &lds_b[c * 512]);
    }
    __syncthreads();   // drains vmcnt -> LDS writes visible
    const int fr = l & 15, fk = (l >> 4) * 8;
    bf16x8 af[MI], bfr[4];
#pragma unroll
    for (int i = 0; i < MI; ++i)
      af[i] = *(const bf16x8*)&lds_a[(wm * (BM / 2) + i * 16 + fr) * 32 + fk];
#pragma unroll
    for (int j = 0; j < 4; ++j)
      bfr[j] = *(const bf16x8*)&lds_b[(wn * 64 + j * 16 + fr) * 32 + fk];
#pragma unroll
    for (int i = 0; i < MI; ++i)
#pragma unroll
      for (int j = 0; j < 4; ++j)
        acc[i][j] = __builtin_amdgcn_mfma_f32_16x16x32_bf16(af[i], bfr[j],
                                                            acc[i][j], 0, 0, 0);
    __syncthreads();   // protect LDS from next iteration's staging
  }

  const LL coff = (fw[0] ? off1 : off0);
  const int er = (l >> 4) * 4, ec = l & 15;   // C/D: col=lane&15, row=quad*4+reg
#pragma unroll
  for (int i = 0; i < MI; ++i) {
#pragma unroll
    for (int j = 0; j < 4; ++j) {
      LL mrow = m0 + wm * (BM / 2) + i * 16 + er;
      LL ncol = n0 + wn * 64 + j * 16 + ec;
      float bs = bias[ncol];
#pragma unroll
      for (int r = 0; r < 4; ++r) {
        float v = acc[i][j][r] + bs;
        if (OUTBF) Cb[coff + (mrow + r) * N + ncol] = (bf16_t)v;
        else       Cf[(mrow + r) * N + ncol] = v;
      }
    }
  }
}

// ==================== fused recurrent step ====================
// gates = h_in @ Whh_p^T + G_t  (Whh_p rows permuted so col 4j+g = gate g of
// hidden unit j; G_t already contains x_t@W_ih_p^T + b_ih + b_hh).
// v2: 64x64 tile, grid (8,64)=512 blocks -> 2 blocks/CU (8 waves/CU);
//     double-buffered LDS, ONE barrier per k-tile (stage t+1 before compute t);
//     bijective XCD swizzle: XCD g owns gate-cols [512g, 512g+512) so its
//     1MB Whh slice + 1MB h fit the 4MB per-XCD L2 and stay hot for 49 steps.
__global__ __launch_bounds__(256, 2)
void lstm_step(const bf16_t* __restrict__ h_in, const bf16_t* __restrict__ Whh,
               const bf16_t* __restrict__ Gt, float* __restrict__ c,
               bf16_t* __restrict__ h_out, float* __restrict__ hid, int t) {
  __shared__ bf16_t lds_a[2][64 * 32];
  __shared__ bf16_t lds_b[2][64 * 32];
  __shared__ float lds_ex[64 * 64];
  const int tid = threadIdx.x;
  const int w = tid >> 6, l = tid & 63;
  // linear dispatch id (gridDim.x == 8); xcd = bid % 8 (round-robin)
  const int bid = blockIdx.x + (blockIdx.y << 3);
  const int g = bid & 7, q = bid >> 3;          // q in [0,64)
  const int m0 = (q & 7) * 64;                  // 8 M-tiles
  const int n0 = ((g << 3) | (q >> 3)) * 64;    // XCD g -> n-tiles [8g, 8g+8)
  const int wm = w & 1, wn = w >> 1;            // 2x2 wave grid, 32x32 each
  f32x4 acc[2][2] = {};
  const int srow = l >> 2, scol = (l & 3) * 8;  // 16-row x 32-col chunk, 16B/lane
  const int fr = l & 15, fk = (l >> 4) * 8;

  auto stage = [&](int buf, int kt) {
    // A: 64 rows = 4 chunks (1 per wave); B: same
    gl_lds16(h_in + (LL)(m0 + w * 16 + srow) * 1024 + kt + scol,
             &lds_a[buf][w * 512]);
    gl_lds16(Whh + (LL)(n0 + w * 16 + srow) * 1024 + kt + scol,
             &lds_b[buf][w * 512]);
  };
  auto compute = [&](int buf) {
    bf16x8 af[2], bfr[2];
#pragma unroll
    for (int i = 0; i < 2; ++i)
      af[i] = *(const bf16x8*)&lds_a[buf][(wm * 32 + i * 16 + fr) * 32 + fk];
#pragma unroll
    for (int j = 0; j < 2; ++j)
      bfr[j] = *(const bf16x8*)&lds_b[buf][(wn * 32 + j * 16 + fr) * 32 + fk];
#pragma unroll
    for (int i = 0; i < 2; ++i)
#pragma unroll
      for (int j = 0; j < 2; ++j)
        acc[i][j] = __builtin_amdgcn_mfma_f32_16x16x32_bf16(af[i], bfr[j],
                                                            acc[i][j], 0, 0, 0);
  };

  stage(0, 0);
  __syncthreads();                      // tile 0 resident
#pragma unroll 1
  for (int kt = 0; kt < 1024; kt += 64) {
    stage(1, kt + 32);                  // async prefetch, in flight under MFMA
    compute(0);
    __syncthreads();                    // drains vmcnt -> buf1 ready
    if (kt + 64 < 1024) stage(0, kt + 64);
    compute(1);
    __syncthreads();
  }

  // exchange gates through LDS so each thread gets full (i,f,g,o) quadruples
  const int er = (l >> 4) * 4, ec = l & 15;
#pragma unroll
  for (int i = 0; i < 2; ++i)
#pragma unroll
    for (int j = 0; j < 2; ++j)
#pragma unroll
      for (int r = 0; r < 4; ++r)
        lds_ex[(wm * 32 + i * 16 + er + r) * 64 + wn * 32 + j * 16 + ec] =
            acc[i][j][r];
  __syncthreads();

  for (int cidx = tid; cidx < 1024; cidx += 256) {
    int ml = cidx >> 4, jl = cidx & 15;       // 64 rows x 16 hidden units
    int m = m0 + ml;
    int j = (n0 >> 2) + jl;
    float4 ge = *(const float4*)&lds_ex[ml * 64 + jl * 4];
    bf16x4 g4 = *(const bf16x4*)(Gt + (LL)m * 4096 + n0 + jl * 4);
    float gi = ge.x + (float)g4[0];
    float gf = ge.y + (float)g4[1];
    float gg = ge.z + (float)g4[2];
    float go = ge.w + (float)g4[3];
    float iv = sigm(gi), fv = sigm(gf), gv = tanh_s(gg), ov = sigm(go);
    LL cij = (LL)m * 1024 + j;
    float cn = fv * c[cij] + iv * gv;
    float hn = ov * tanh_s(cn);
    c[cij] = cn;
    h_out[cij] = (bf16_t)hn;
    hid[((LL)m * 49 + t) * 1024 + j] = hn;
  }
}

// ==================== prep kernels ====================
__global__ __launch_bounds__(256)
void cvt_f2b(const float* __restrict__ src, bf16_t* __restrict__ dst, LL n4) {
  LL i = (LL)blockIdx.x * blockDim.x + threadIdx.x;
  LL stride = (LL)gridDim.x * blockDim.x;
  for (; i < n4; i += stride) {
    float4 v = *(const float4*)(src + i * 4);
    bf16x4 o;
    o[0] = (bf16_t)v.x; o[1] = (bf16_t)v.y; o[2] = (bf16_t)v.z; o[3] = (bf16_t)v.w;
    *(bf16x4*)(dst + i * 4) = o;
  }
}

// permuted row p = 4*j + g  maps from original row  g*1024 + j
__global__ __launch_bounds__(256)
void permute_w(const float* __restrict__ W, bf16_t* __restrict__ Wp) {
  int p = blockIdx.x;
  int r = (p & 3) * 1024 + (p >> 2);
  float4 v = *(const float4*)(W + (LL)r * 1024 + threadIdx.x * 4);
  bf16x4 o;
  o[0] = (bf16_t)v.x; o[1] = (bf16_t)v.y; o[2] = (bf16_t)v.z; o[3] = (bf16_t)v.w;
  *(bf16x4*)(Wp + (LL)p * 1024 + threadIdx.x * 4) = o;
}

__global__ __launch_bounds__(256)
void bias_comb(const float* __restrict__ bih, const float* __restrict__ bhh,
               float* __restrict__ bp) {
  int p = blockIdx.x * blockDim.x + threadIdx.x;
  int r = (p & 3) * 1024 + (p >> 2);
  bp[p] = bih[r] + bhh[r];
}

// Xb[slot][n][:] = bf16(emb[questions[n][tq]]) ; slot = tq + (fw?1:0)
__global__ __launch_bounds__(256)
void gather_emb(const int* __restrict__ q, const float* __restrict__ emb,
                bf16_t* __restrict__ Xb, const int* __restrict__ fw) {
  int b = blockIdx.x;         // 48*512 blocks
  int tq = b >> 9;
  int n = b & 511;
  int slot = fw[0] ? tq + 1 : tq;
  int row = q[n * 48 + tq];
  float4 v = *(const float4*)(emb + (LL)row * 1024 + threadIdx.x * 4);
  bf16x4 o;
  o[0] = (bf16_t)v.x; o[1] = (bf16_t)v.y; o[2] = (bf16_t)v.z; o[3] = (bf16_t)v.w;
  *(bf16x4*)(Xb + ((LL)slot * 512 + n) * 1024 + threadIdx.x * 4) = o;
}

// ==================== launch ====================
extern "C" void kernel_launch(void* const* d_in, const int* in_sizes, int n_in,
                              void* d_out, int out_size, void* d_ws,
                              size_t ws_size, hipStream_t stream) {
  const int*   questions = (const int*)  d_in[0];
  const float* img       = (const float*)d_in[1];
  const float* emb       = (const float*)d_in[2];
  const float* W_img     = (const float*)d_in[3];
  const float* b_img     = (const float*)d_in[4];
  const float* W_ih      = (const float*)d_in[5];
  const float* W_hh      = (const float*)d_in[6];
  const float* b_ih      = (const float*)d_in[7];
  const float* b_hh      = (const float*)d_in[8];
  const float* W_out     = (const float*)d_in[9];
  const float* b_out     = (const float*)d_in[10];
  const int*   fw        = (const int*)  d_in[11];

  char* ws = (char*)d_ws;
  size_t off = 0;
  auto alloc = [&](size_t bytes) {
    char* p = ws + off;
    off += (bytes + 255) & ~(size_t)255;
    return p;
  };
  bf16_t* Xb    = (bf16_t*)alloc((size_t)49 * 512 * 1024 * 2);   // 51.4 MB
  bf16_t* G     = (bf16_t*)alloc((size_t)49 * 512 * 4096 * 2);   // 205.5 MB
  bf16_t* Wp_ih = (bf16_t*)alloc((size_t)4096 * 1024 * 2);
  bf16_t* Wp_hh = (bf16_t*)alloc((size_t)4096 * 1024 * 2);
  bf16_t* Woutb = (bf16_t*)alloc((size_t)32000 * 1024 * 2);      // 65.5 MB
  bf16_t* Wimgb = (bf16_t*)alloc((size_t)1024 * 4096 * 2);
  bf16_t* imgb  = (bf16_t*)alloc((size_t)512 * 4096 * 2);
  float*  biasp = (float*) alloc((size_t)4096 * 4);
  bf16_t* h0    = (bf16_t*)alloc((size_t)512 * 1024 * 2);
  bf16_t* h1    = (bf16_t*)alloc((size_t)512 * 1024 * 2);
  float*  cbuf  = (float*) alloc((size_t)512 * 1024 * 4);

  float* out0 = (float*)d_out;
  float* hid  = out0 + (size_t)512 * 32000;

  hipMemsetAsync(h0, 0, (size_t)512 * 1024 * 2, stream);
  hipMemsetAsync(cbuf, 0, (size_t)512 * 1024 * 4, stream);

  cvt_f2b<<<dim3(2048), dim3(256), 0, stream>>>(W_out, Woutb, (LL)32000 * 1024 / 4);
  cvt_f2b<<<dim3(1024), dim3(256), 0, stream>>>(W_img, Wimgb, (LL)1024 * 4096 / 4);
  cvt_f2b<<<dim3(512),  dim3(256), 0, stream>>>(img,   imgb,  (LL)512 * 4096 / 4);
  permute_w<<<dim3(4096), dim3(256), 0, stream>>>(W_ih, Wp_ih);
  permute_w<<<dim3(4096), dim3(256), 0, stream>>>(W_hh, Wp_hh);
  bias_comb<<<dim3(16), dim3(256), 0, stream>>>(b_ih, b_hh, biasp);
  gather_emb<<<dim3(48 * 512), dim3(256), 0, stream>>>(questions, emb, Xb, fw);

  // emb_i = img @ W_img^T + b_img  -> Xb slot (fw ? 0 : 48), bf16
  gemm_bt<64, 1><<<dim3(8, 8), dim3(256), 0, stream>>>(
      imgb, Wimgb, b_img, Xb, nullptr, 1024, 4096, fw,
      (LL)48 * 512 * 1024, (LL)0);

  // G = Xb @ Wp_ih^T + (b_ih+b_hh)  (permuted cols), bf16  [25088 x 4096]
  gemm_bt<128, 1><<<dim3(196, 32), dim3(256), 0, stream>>>(
      Xb, Wp_ih, biasp, G, nullptr, 4096, 1024, fw, 0, 0);

  for (int t = 0; t < 49; ++t) {
    const bf16_t* hin = (t & 1) ? h1 : h0;
    bf16_t* hout = (t & 1) ? h0 : h1;
    lstm_step<<<dim3(8, 64), dim3(256), 0, stream>>>(
        hin, Wp_hh, G + (LL)t * 512 * 4096, cbuf, hout, hid, t);
  }

  // output = h_49 @ W_out^T + b_out, fp32  [512 x 32000]
  gemm_bt<128, 0><<<dim3(4, 250), dim3(256), 0, stream>>>(
      h1, Woutb, b_out, nullptr, out0, 32000, 1024, fw, 0, 0);
}